// Round 7
// baseline (62.898 us; speedup 1.0000x reference)
//
#include <hip/hip_runtime.h>
#include <hip/hip_bf16.h>
#include <math.h>

#define NQ 20
#define NB 32

// Thread t = b*NQ + q evolves the 2-component complex state of qubit q, batch b
// through 6 layers of (RX(w0), RZ(w1), RX(w2), RX(x[:,col])).
// Algebra verified symbolically vs reference. Observable factorizes:
// O[b] = prod_q (|s0|^2 - |s1|^2)   (sign(k)=(-1)^popcount, |wf|^2 factorizes).
//
// WORLD MODEL (settled r0-r6): reference outputs are complex64 -> harness
// maps non-bf16 to a FLOAT32 buffer; numpy .astype(float32) drops imag.
//   out_size==1312 (float32):  [0..1280): state.real, (b,q,j) -> 2*(b*NQ+q)+j
//                              [1280..1312): O.real per b
//   (fallback out_size==2624: bf16 interleaved — believed impossible)
// Evidence: r2-r6 wrote bf16 bits into the f32 buffer (garbage floats, absmax
// 1.4-1.9); r1 wrote f32 but interleaved complex (wrong layout); threshold
// 0.0199 < 8*2^-8 bf16 floor => no bf16 anywhere; out npz = 5248 B = 1312 f32.
__global__ __launch_bounds__(NB * NQ) void qc_kernel(
    const float* __restrict__ x,       // (32, 8, 20) fp32
    const float* __restrict__ w,       // (6, 3, 32, 20) fp32
    float* __restrict__ outf,          // f32 view of d_out
    __hip_bfloat16* __restrict__ outb, // bf16 view of d_out (fallback only)
    const int f32_mode) {
  __shared__ float zexp[NB][NQ];

  const int t = threadIdx.x;           // 0..639
  const int b = t / NQ;
  const int q = t - b * NQ;

  float s0r = 1.0f, s0i = 0.0f, s1r = 0.0f, s1i = 0.0f;

  const int cols[6] = {0, 1, 2, 5, 6, 7};

#pragma unroll
  for (int i = 0; i < 6; ++i) {
    // --- RX(w[i][0]) ---
    {
      const float a = w[((i * 3 + 0) * NB + b) * NQ + q];
      float sn, c; sincosf(0.5f * a, &sn, &c);
      const float t0r = c * s0r + sn * s1i;
      const float t0i = c * s0i - sn * s1r;
      const float t1r = c * s1r + sn * s0i;
      const float t1i = c * s1i - sn * s0r;
      s0r = t0r; s0i = t0i; s1r = t1r; s1i = t1i;
    }
    // --- RZ(w[i][1]) : s0 *= e^{-ia/2}, s1 *= e^{+ia/2} ---
    {
      const float a = w[((i * 3 + 1) * NB + b) * NQ + q];
      float sn, c; sincosf(0.5f * a, &sn, &c);
      const float t0r = s0r * c + s0i * sn;
      const float t0i = s0i * c - s0r * sn;
      const float t1r = s1r * c - s1i * sn;
      const float t1i = s1i * c + s1r * sn;
      s0r = t0r; s0i = t0i; s1r = t1r; s1i = t1i;
    }
    // --- RX(w[i][2]) ---
    {
      const float a = w[((i * 3 + 2) * NB + b) * NQ + q];
      float sn, c; sincosf(0.5f * a, &sn, &c);
      const float t0r = c * s0r + sn * s1i;
      const float t0i = c * s0i - sn * s1r;
      const float t1r = c * s1r + sn * s0i;
      const float t1i = c * s1i - sn * s0r;
      s0r = t0r; s0i = t0i; s1r = t1r; s1i = t1i;
    }
    // --- RX(x[:, col]) ---
    {
      const float a = x[(b * 8 + cols[i]) * NQ + q];
      float sn, c; sincosf(0.5f * a, &sn, &c);
      const float t0r = c * s0r + sn * s1i;
      const float t0i = c * s0i - sn * s1r;
      const float t1r = c * s1r + sn * s0i;
      const float t1i = c * s1i - sn * s0r;
      s0r = t0r; s0i = t0i; s1r = t1r; s1i = t1i;
    }
  }

  // Per-qubit z-expectation for the factorized observable.
  zexp[b][q] = (s0r * s0r + s0i * s0i) - (s1r * s1r + s1i * s1i);

  if (f32_mode) {
    // float32 buffer, imag dropped: state.real as (b,q,2) -> [2t, 2t+1]
    reinterpret_cast<float2*>(outf)[t] = make_float2(s0r, s1r);
  } else {
    // fallback: bf16 interleaved complex
    struct alignas(8) bf16x4 { __hip_bfloat16 a, b, c, d; } pk;
    pk.a = __float2bfloat16(s0r);
    pk.b = __float2bfloat16(s0i);
    pk.c = __float2bfloat16(s1r);
    pk.d = __float2bfloat16(s1i);
    reinterpret_cast<bf16x4*>(outb)[t] = pk;
  }

  __syncthreads();

  if (t < NB) {
    float p = 1.0f;
#pragma unroll
    for (int qq = 0; qq < NQ; ++qq) p *= zexp[t][qq];
    if (f32_mode) {
      outf[1280 + t] = p;               // O.real (sign preserved)
    } else {
      outb[2560 + 2 * t + 0] = __float2bfloat16(p);
      outb[2560 + 2 * t + 1] = __float2bfloat16(0.0f);
    }
  }
}

extern "C" void kernel_launch(void* const* d_in, const int* in_sizes, int n_in,
                              void* d_out, int out_size, void* d_ws, size_t ws_size,
                              hipStream_t stream) {
  // Documented dict order: x first, weights second. Relative-size guard is a
  // no-op in the documented world (5120 < 11520) and protects against units.
  const float* x;
  const float* w;
  if (in_sizes[0] <= in_sizes[1]) {
    x = (const float*)d_in[0];
    w = (const float*)d_in[1];
  } else {
    w = (const float*)d_in[0];
    x = (const float*)d_in[1];
  }

  const int f32_mode = (out_size == 1312) ? 1 : 0;

  qc_kernel<<<1, NB * NQ, 0, stream>>>(
      x, w, (float*)d_out, (__hip_bfloat16*)d_out, f32_mode);
}

// Round 8
// 55.412 us; speedup vs baseline: 1.1351x; 1.1351x over previous
//
#include <hip/hip_runtime.h>
#include <hip/hip_bf16.h>
#include <math.h>

#define NQ 20
#define NB 32

// WORLD MODEL (settled, r7 PASSED absmax 4.6e-9):
//   inputs dict order: d_in[0]=x (32,8,20) f32, d_in[1]=weights (6,3,32,20) f32
//   d_out: FLOAT32, 1312 elements (complex64 ref .astype(f32), imag dropped):
//     [0..1280): state.real, (b,q,j) -> 2*(b*NQ+q)+j   [1280..1312): O.real
//
// Block b = batch b (32 blocks x 64 threads, 1 wave). Lane q<20 evolves the
// 2-amplitude state of qubit q through 6 layers of (RX,RZ,RX,RX(data)).
// Observable factorizes: O[b] = prod_q (|s0|^2 - |s1|^2); computed by a
// wave-local __shfl_xor product butterfly (lanes >=20 contribute 1.0).
// Native trig (__sinf/__cosf -> v_sin/v_cos_f32, revolutions pre-scale emitted
// by compiler) is safe: |angle/2| <= ~2.7 rad, err ~1e-6 << 2e-2 threshold.
__global__ __launch_bounds__(64) void qc_kernel(
    const float* __restrict__ x,       // (32, 8, 20)
    const float* __restrict__ w,       // (6, 3, 32, 20)
    float* __restrict__ out) {
  const int b = blockIdx.x;            // batch
  const int q = threadIdx.x;           // lane; active if q < NQ

  float s0r = 1.0f, s0i = 0.0f, s1r = 0.0f, s1i = 0.0f;

  if (q < NQ) {
    const int cols[6] = {0, 1, 2, 5, 6, 7};
#pragma unroll
    for (int i = 0; i < 6; ++i) {
      // RX(w[i][0])
      {
        const float a = 0.5f * w[((i * 3 + 0) * NB + b) * NQ + q];
        const float c = __cosf(a), sn = __sinf(a);
        const float t0r = c * s0r + sn * s1i;
        const float t0i = c * s0i - sn * s1r;
        const float t1r = c * s1r + sn * s0i;
        const float t1i = c * s1i - sn * s0r;
        s0r = t0r; s0i = t0i; s1r = t1r; s1i = t1i;
      }
      // RZ(w[i][1]): s0 *= e^{-ia/2}, s1 *= e^{+ia/2}
      {
        const float a = 0.5f * w[((i * 3 + 1) * NB + b) * NQ + q];
        const float c = __cosf(a), sn = __sinf(a);
        const float t0r = s0r * c + s0i * sn;
        const float t0i = s0i * c - s0r * sn;
        const float t1r = s1r * c - s1i * sn;
        const float t1i = s1i * c + s1r * sn;
        s0r = t0r; s0i = t0i; s1r = t1r; s1i = t1i;
      }
      // RX(w[i][2])
      {
        const float a = 0.5f * w[((i * 3 + 2) * NB + b) * NQ + q];
        const float c = __cosf(a), sn = __sinf(a);
        const float t0r = c * s0r + sn * s1i;
        const float t0i = c * s0i - sn * s1r;
        const float t1r = c * s1r + sn * s0i;
        const float t1i = c * s1i - sn * s0r;
        s0r = t0r; s0i = t0i; s1r = t1r; s1i = t1i;
      }
      // RX(x[:, col])
      {
        const float a = 0.5f * x[(b * 8 + cols[i]) * NQ + q];
        const float c = __cosf(a), sn = __sinf(a);
        const float t0r = c * s0r + sn * s1i;
        const float t0i = c * s0i - sn * s1r;
        const float t1r = c * s1r + sn * s0i;
        const float t1i = c * s1i - sn * s0r;
        s0r = t0r; s0i = t0i; s1r = t1r; s1i = t1i;
      }
    }
    // state.real write: (b,q,{0,1}) -> float2 at index b*NQ+q
    reinterpret_cast<float2*>(out)[b * NQ + q] = make_float2(s0r, s1r);
  }

  // Factorized observable: product over 20 qubits via 64-lane butterfly.
  float z = (q < NQ)
                ? (s0r * s0r + s0i * s0i) - (s1r * s1r + s1i * s1i)
                : 1.0f;
#pragma unroll
  for (int m = 1; m < 64; m <<= 1) z *= __shfl_xor(z, m, 64);
  if (q == 0) out[2 * NB * NQ + b] = z;  // O.real at [1280 + b]
}

extern "C" void kernel_launch(void* const* d_in, const int* in_sizes, int n_in,
                              void* d_out, int out_size, void* d_ws, size_t ws_size,
                              hipStream_t stream) {
  // Dict order confirmed; relative-size guard kept as a no-op safety net.
  const float* x;
  const float* w;
  if (in_sizes[0] <= in_sizes[1]) {
    x = (const float*)d_in[0];
    w = (const float*)d_in[1];
  } else {
    w = (const float*)d_in[0];
    x = (const float*)d_in[1];
  }
  qc_kernel<<<NB, 64, 0, stream>>>(x, w, (float*)d_out);
}